// Round 6
// baseline (1305.882 us; speedup 1.0000x reference)
//
#include <hip/hip_runtime.h>
#include <math.h>

namespace {

constexpr int TSEQ   = 2048;
constexpr int DIN    = 16;
constexpr int NH1    = 5;
constexpr int NH2    = 50;
constexpr int NCLS   = 20;
constexpr int CHUNK  = 64;
constexpr int NCHUNK = TSEQ / CHUNK;
constexpr int BATCH  = 256;
constexpr int GXS    = 21;   // gx row stride (odd -> conflict-free)
constexpr int XS     = 17;   // s_x row stride (odd -> conflict-free)

// No clamp: exp(+inf)->inf, rcp(inf)->0 — still correct; inputs bounded.
__device__ __forceinline__ float fast_sigm(float x) {
    return __fdividef(1.f, 1.f + __expf(-x));
}
// tanh(x) = 2*sigm(2x) - 1
__device__ __forceinline__ float fast_tanh(float x) {
    return fmaf(2.f, fast_sigm(2.f * x), -1.f);
}

// quad_perm DPP: VALU-speed cross-lane within aligned quads (no DS pipe).
template <int CTRL>
__device__ __forceinline__ float qperm(float v) {
    int i = __builtin_bit_cast(int, v);
    int r = __builtin_amdgcn_update_dpp(i, i, CTRL, 0xf, 0xf, false);
    return __builtin_bit_cast(float, r);
}
__device__ __forceinline__ float rdlane(float v, int lane) {
    return __builtin_bit_cast(float,
        __builtin_amdgcn_readlane(__builtin_bit_cast(int, v), lane));
}

struct L1State {
    float c1;
    float h0, h1, h2, h3, h4;   // wave-uniform (readlane) -> SGPRs
};

// One L1 timestep. Lane 4j+g owns row r=g*5+j (j<5). DPP gate gather,
// readlane h1 broadcast — no LDS.
__device__ __forceinline__ void l1_step(float gx, float bias1,
                                        const float* __restrict__ w1h,
                                        float isc1, float osc1, float off1,
                                        L1State& st) {
    float g1 = gx + bias1;
    g1 = fmaf(st.h0, w1h[0], g1);
    g1 = fmaf(st.h1, w1h[1], g1);
    g1 = fmaf(st.h2, w1h[2], g1);
    g1 = fmaf(st.h3, w1h[3], g1);
    g1 = fmaf(st.h4, w1h[4], g1);
    float act = fmaf(osc1, fast_sigm(isc1 * g1), off1);
    float f_ = qperm<0xB1>(act);
    float gg = qperm<0x4E>(act);
    float o_ = qperm<0x1B>(act);
    st.c1 = fmaf(f_, st.c1, act * gg);          // valid on lanes 4j+0
    float h1me = o_ * fast_tanh(st.c1);
    st.h0 = rdlane(h1me, 0);
    st.h1 = rdlane(h1me, 4);
    st.h2 = rdlane(h1me, 8);
    st.h3 = rdlane(h1me, 12);
    st.h4 = rdlane(h1me, 16);
}

// One block = 4 waves = one batch element. Lane owns (unit,gate) row of L2.
// h2 crosses waves via ONE ds_read_b32 per wave + v_readlane SGPR broadcast
// (kills the 13x ds_read_b128 LDS-pipe bottleneck of R5).
__global__ __launch_bounds__(256, 1) void lstm_fused_kernel(
    const float* __restrict__ x,     // (256,2048,16)
    const float* __restrict__ W1ih,  // (20,16)
    const float* __restrict__ W1hh,  // (20,5)
    const float* __restrict__ b1ih,  // (20)
    const float* __restrict__ b1hh,  // (20)
    const float* __restrict__ W2ih,  // (200,5)
    const float* __restrict__ W2hh,  // (200,50)
    const float* __restrict__ b2ih,  // (200)
    const float* __restrict__ b2hh,  // (200)
    const float* __restrict__ Wfc,   // (20,50)
    const float* __restrict__ bfc,   // (20)
    float* __restrict__ out)         // result(256,20) ++ last(256,50)
{
    const int b    = blockIdx.x;
    const int tid  = threadIdx.x;
    const int lane = tid & 63;
    const int wv   = tid >> 6;

    __shared__ __align__(16) float s_w1[NCLS * DIN];   // 320
    __shared__ __align__(16) float s_x[CHUNK * XS];    // padded x stage
    __shared__ __align__(16) float s_gx[CHUNK * GXS];  // x-part gates
    __shared__ __align__(16) float s_h2[2][52];        // h2 double buffer

    for (int i = tid; i < NCLS * DIN; i += 256) s_w1[i] = W1ih[i];
    if (tid < 52) { s_h2[0][tid] = 0.f; s_h2[1][tid] = 0.f; }

    // ---- layer-1: lane 4j+g owns row r = g*5+j (lanes 0..19) ----
    const int r1 = (lane < NCLS) ? ((lane & 3) * NH1 + (lane >> 2)) : 0;
    float w1h[NH1];
    #pragma unroll
    for (int j = 0; j < NH1; ++j) w1h[j] = W1hh[r1 * NH1 + j];
    const float bias1 = b1ih[r1] + b1hh[r1];
    const bool  isg1  = ((lane & 3) == 2) && (lane < NCLS);
    const float isc1  = isg1 ? 2.f : 1.f;
    const float osc1  = isg1 ? 2.f : 1.f;
    const float off1  = isg1 ? -1.f : 0.f;

    // ---- layer-2 per-lane (unit,gate) row ----
    const int ul   = lane >> 2;
    const int g    = lane & 3;
    const int nu   = (wv < 3) ? 13 : 11;
    const bool on2 = (ul < nu);
    const int u    = on2 ? (wv * 13 + ul) : 0;
    const int row  = g * NH2 + u;

    float w2[NH2];                               // 50 VGPRs, register-resident
    {
        const float2* wr = (const float2*)(W2hh + row * NH2);  // 200B rows
        #pragma unroll
        for (int j = 0; j < 25; ++j) {
            float2 v = wr[j];
            w2[2 * j]     = v.x;
            w2[2 * j + 1] = v.y;
        }
    }
    float w2i[NH1];
    #pragma unroll
    for (int d = 0; d < NH1; ++d) w2i[d] = W2ih[row * NH1 + d];
    const float bias2 = b2ih[row] + b2hh[row];
    const bool  isg2  = (g == 2);
    const float isc2  = isg2 ? 2.f : 1.f;
    const float osc2  = isg2 ? 2.f : 1.f;
    const float off2  = isg2 ? -1.f : 0.f;

    L1State st = {0.f, 0.f, 0.f, 0.f, 0.f, 0.f};
    float c2 = 0.f;

    const float* xb = x + (size_t)b * TSEQ * DIN;
    const int hl = (lane < 52) ? lane : 0;       // h2 distribution slot

    __syncthreads();

    #pragma unroll 1
    for (int c = 0; c < NCHUNK; ++c) {
        // ---- stage x chunk into padded rows (coalesced global read) ----
        {
            float4 v = ((const float4*)(xb + (size_t)c * CHUNK * DIN))[tid];
            const int stp = tid >> 2, col = (tid & 3) * 4;
            float* dst = s_x + stp * XS + col;
            dst[0] = v.x; dst[1] = v.y; dst[2] = v.z; dst[3] = v.w;
        }
        __syncthreads();

        // ---- x-part gates: thread = (step, q); 5 rows each ----
        {
            const int stp = tid >> 2, q = tid & 3;
            const float* xs = s_x + stp * XS;
            float x0 = xs[0],  x1 = xs[1],  x2 = xs[2],  x3 = xs[3];
            float x4 = xs[4],  x5 = xs[5],  x6 = xs[6],  x7 = xs[7];
            float x8 = xs[8],  x9 = xs[9],  xA = xs[10], xB = xs[11];
            float xC = xs[12], xD = xs[13], xE = xs[14], xF = xs[15];
            #pragma unroll
            for (int r = 0; r < 5; ++r) {
                const int rw = q * 5 + r;
                const float* wr = s_w1 + rw * DIN;
                float s = wr[0] * x0;
                s = fmaf(wr[1],  x1, s); s = fmaf(wr[2],  x2, s); s = fmaf(wr[3],  x3, s);
                s = fmaf(wr[4],  x4, s); s = fmaf(wr[5],  x5, s); s = fmaf(wr[6],  x6, s);
                s = fmaf(wr[7],  x7, s); s = fmaf(wr[8],  x8, s); s = fmaf(wr[9],  x9, s);
                s = fmaf(wr[10], xA, s); s = fmaf(wr[11], xB, s); s = fmaf(wr[12], xC, s);
                s = fmaf(wr[13], xD, s); s = fmaf(wr[14], xE, s); s = fmaf(wr[15], xF, s);
                s_gx[stp * GXS + rw] = s;
            }
        }
        __syncthreads();

        // ---- chunk preamble: L1 for the chunk's step 0 ----
        l1_step(s_gx[r1], bias1, w1h, isc1, osc1, off1, st);

        // ---- one timestep; SRC/DST are compile-time buffer indices ----
        #define LSTM_STEP(SRC, DST, TT, DO_L1)                                     \
        {                                                                          \
            float hv = s_h2[SRC][hl];            /* one ds_read_b32 per wave */    \
            float gx_next = s_gx[(TT + 1) * GXS + r1];                             \
            float s0 = bias2, s1 = 0.f, s2 = 0.f, s3 = 0.f;                        \
            _Pragma("unroll")                                                      \
            for (int k = 0; k < 48; k += 4) {                                      \
                s0 = fmaf(rdlane(hv, k),     w2[k],     s0);                       \
                s1 = fmaf(rdlane(hv, k + 1), w2[k + 1], s1);                       \
                s2 = fmaf(rdlane(hv, k + 2), w2[k + 2], s2);                       \
                s3 = fmaf(rdlane(hv, k + 3), w2[k + 3], s3);                       \
            }                                                                      \
            s0 = fmaf(rdlane(hv, 48), w2[48], s0);                                 \
            s1 = fmaf(rdlane(hv, 49), w2[49], s1);                                 \
            s2 = fmaf(st.h0, w2i[0], s2);                                          \
            s3 = fmaf(st.h1, w2i[1], s3);                                          \
            s2 = fmaf(st.h2, w2i[2], s2);                                          \
            s3 = fmaf(st.h3, w2i[3], s3);                                          \
            s2 = fmaf(st.h4, w2i[4], s2);                                          \
            if (DO_L1)                                                             \
                l1_step(gx_next, bias1, w1h, isc1, osc1, off1, st);                \
            float pre = (s0 + s1) + (s2 + s3);                                     \
            float act2 = fmaf(osc2, fast_sigm(isc2 * pre), off2);                  \
            float v1 = qperm<0xB1>(act2);                                          \
            float v2 = qperm<0x4E>(act2);                                          \
            float v3 = qperm<0x1B>(act2);                                          \
            c2 = fmaf(v1, c2, act2 * v2);                                          \
            float hn = v3 * fast_tanh(c2);                                         \
            if (g == 0 && on2) s_h2[DST][u] = hn;                                  \
            __syncthreads();                                                       \
        }

        #pragma unroll 1
        for (int tt = 0; tt < CHUNK; tt += 2) {
            LSTM_STEP(0, 1, tt, true)
            LSTM_STEP(1, 0, tt + 1, (tt < CHUNK - 2))
        }
        #undef LSTM_STEP
    }

    // ---- outputs: result(256,20) @0, last(256,50) @5120 ----
    if (tid < NH2) out[BATCH * NCLS + b * NH2 + tid] = s_h2[0][tid];
    if (tid < NCLS) {
        float acc = bfc[tid];
        const float* wr = Wfc + tid * NH2;
        #pragma unroll
        for (int j = 0; j < NH2; ++j) acc = fmaf(s_h2[0][j], wr[j], acc);
        out[b * NCLS + tid] = acc;
    }
}

} // namespace

extern "C" void kernel_launch(void* const* d_in, const int* in_sizes, int n_in,
                              void* d_out, int out_size, void* d_ws, size_t ws_size,
                              hipStream_t stream) {
    (void)in_sizes; (void)n_in; (void)d_ws; (void)ws_size; (void)out_size;
    const float* x    = (const float*)d_in[0];
    const float* W1ih = (const float*)d_in[1];
    const float* W1hh = (const float*)d_in[2];
    const float* b1ih = (const float*)d_in[3];
    const float* b1hh = (const float*)d_in[4];
    const float* W2ih = (const float*)d_in[5];
    const float* W2hh = (const float*)d_in[6];
    const float* b2ih = (const float*)d_in[7];
    const float* b2hh = (const float*)d_in[8];
    const float* Wfc  = (const float*)d_in[9];
    const float* bfc  = (const float*)d_in[10];

    lstm_fused_kernel<<<dim3(BATCH), dim3(256), 0, stream>>>(
        x, W1ih, W1hh, b1ih, b1hh, W2ih, W2hh, b2ih, b2hh, Wfc, bfc,
        (float*)d_out);
}

// Round 7
// 989.844 us; speedup vs baseline: 1.3193x; 1.3193x over previous
//
#include <hip/hip_runtime.h>
#include <math.h>

namespace {

constexpr int TSEQ   = 2048;
constexpr int DIN    = 16;
constexpr int NH1    = 5;
constexpr int NH2    = 50;
constexpr int NCLS   = 20;
constexpr int CHUNK  = 64;
constexpr int NCHUNK = TSEQ / CHUNK;
constexpr int BATCH  = 256;
constexpr int GXS    = 21;   // gx row stride
constexpr int NPAD   = 64;   // padded unit count (rows = gate*64 + unit)

// No clamp: exp(+inf)->inf, rcp(inf)->0 — still correct; inputs bounded.
__device__ __forceinline__ float fast_sigm(float x) {
    return __fdividef(1.f, 1.f + __expf(-x));
}
// tanh(x) = 2*sigm(2x) - 1
__device__ __forceinline__ float fast_tanh(float x) {
    return fmaf(2.f, fast_sigm(2.f * x), -1.f);
}

// quad_perm DPP: VALU-speed cross-lane within aligned quads.
template <int CTRL>
__device__ __forceinline__ float qperm(float v) {
    int i = __builtin_bit_cast(int, v);
    int r = __builtin_amdgcn_update_dpp(i, i, CTRL, 0xf, 0xf, false);
    return __builtin_bit_cast(float, r);
}
__device__ __forceinline__ float rdlane(float v, int lane) {
    return __builtin_bit_cast(float,
        __builtin_amdgcn_readlane(__builtin_bit_cast(int, v), lane));
}

struct L1State {
    float c1;
    float h0, h1, h2, h3, h4;   // wave-uniform -> SGPRs
};

// One L1 timestep. Lane 4j+g owns row r=g*5+j (j<5).
__device__ __forceinline__ void l1_step(float gx, float bias1,
                                        const float* __restrict__ w1h,
                                        float isc1, float osc1, float off1,
                                        L1State& st) {
    float g1 = gx + bias1;
    g1 = fmaf(st.h0, w1h[0], g1);
    g1 = fmaf(st.h1, w1h[1], g1);
    g1 = fmaf(st.h2, w1h[2], g1);
    g1 = fmaf(st.h3, w1h[3], g1);
    g1 = fmaf(st.h4, w1h[4], g1);
    float act = fmaf(osc1, fast_sigm(isc1 * g1), off1);
    float f_ = qperm<0xB1>(act);
    float gg = qperm<0x4E>(act);
    float o_ = qperm<0x1B>(act);
    st.c1 = fmaf(f_, st.c1, act * gg);          // valid on lanes 4j+0
    float h1me = o_ * fast_tanh(st.c1);
    st.h0 = rdlane(h1me, 0);
    st.h1 = rdlane(h1me, 4);
    st.h2 = rdlane(h1me, 8);
    st.h3 = rdlane(h1me, 12);
    st.h4 = rdlane(h1me, 16);
}

// One block = 4 waves = one batch element. Split-K L2 matvec:
// wave w owns K-slice (units 13w..13w+12) of h2 in SGPRs (readlane from its
// own combine lanes — h2 never round-trips through LDS). Partial sums cross
// waves through a tiny double-buffered LDS array; ONE barrier per step.
__global__ __launch_bounds__(256, 1) void lstm_fused_kernel(
    const float* __restrict__ x,     // (256,2048,16)
    const float* __restrict__ W1ih,  // (20,16)
    const float* __restrict__ W1hh,  // (20,5)
    const float* __restrict__ b1ih,  // (20)
    const float* __restrict__ b1hh,  // (20)
    const float* __restrict__ W2ih,  // (200,5)
    const float* __restrict__ W2hh,  // (200,50)
    const float* __restrict__ b2ih,  // (200)
    const float* __restrict__ b2hh,  // (200)
    const float* __restrict__ Wfc,   // (20,50)
    const float* __restrict__ bfc,   // (20)
    float* __restrict__ out)         // result(256,20) ++ last(256,50)
{
    const int b    = blockIdx.x;
    const int tid  = threadIdx.x;
    const int lane = tid & 63;
    const int wv   = tid >> 6;

    __shared__ float s_w1[NCLS * DIN];                     // 320
    __shared__ __align__(16) float s_x[CHUNK * DIN];       // x stage
    __shared__ float s_gx[(CHUNK + 1) * GXS];              // x-part gates (+pad row)
    __shared__ __align__(16) float s_part[2][4][4 * NPAD]; // partials, dbuf (8 KB)
    __shared__ float s_h2[NH2];                            // final-h2 mirror

    for (int i = tid; i < NCLS * DIN; i += 256) s_w1[i] = W1ih[i];
    if (tid < NH2) s_h2[tid] = 0.f;

    // ---- layer-1: lane 4j+g owns row r = g*5+j (lanes 0..19) ----
    const int r1 = (lane < NCLS) ? ((lane & 3) * NH1 + (lane >> 2)) : 0;
    float w1h[NH1];
    #pragma unroll
    for (int j = 0; j < NH1; ++j) w1h[j] = W1hh[r1 * NH1 + j];
    const float bias1 = b1ih[r1] + b1hh[r1];
    const bool  isg1  = ((lane & 3) == 2) && (lane < NCLS);
    const float isc1  = isg1 ? 2.f : 1.f;
    const float osc1  = isg1 ? 2.f : 1.f;
    const float off1  = isg1 ? -1.f : 0.f;

    // ---- partial-phase weights: lane owns padded rows 4*lane..4*lane+3,
    //      K-slice = units 13*wv .. 13*wv+12 (52 VGPRs) ----
    float wp[4][13];
    #pragma unroll
    for (int i = 0; i < 4; ++i) {
        const int pr = 4 * lane + i;     // padded row 0..255
        const int pg = pr >> 6;          // gate
        const int pu = pr & 63;          // padded unit
        #pragma unroll
        for (int kk = 0; kk < 13; ++kk) {
            const int k = wv * 13 + kk;  // global K (h2 unit index)
            wp[i][kk] = (pu < NH2 && k < NH2) ? W2hh[(pg * NH2 + pu) * NH2 + k]
                                              : 0.f;
        }
    }

    // ---- combine-phase: lane = 4*ul+g -> unit u = 13*wv+ul (52 active) ----
    const int ul   = lane >> 2;
    const int g    = lane & 3;
    const bool onc = (ul < 13);
    const int u    = wv * 13 + (onc ? ul : 0);     // 0..51 (50,51 = pad)
    const bool ureal = onc && (u < NH2);
    const int crow = g * NPAD + u;                 // padded row to gather
    float w2i[NH1];
    float bias2;
    if (ureal) {
        const int rr = g * NH2 + u;
        #pragma unroll
        for (int d = 0; d < NH1; ++d) w2i[d] = W2ih[rr * NH1 + d];
        bias2 = b2ih[rr] + b2hh[rr];
    } else {
        #pragma unroll
        for (int d = 0; d < NH1; ++d) w2i[d] = 0.f;
        bias2 = 0.f;
    }
    const bool  isg2 = (g == 2);
    const float isc2 = isg2 ? 2.f : 1.f;
    const float osc2 = isg2 ? 2.f : 1.f;
    const float off2 = isg2 ? -1.f : 0.f;

    float hsl[13];                       // wave's h2 K-slice (SGPRs)
    #pragma unroll
    for (int k = 0; k < 13; ++k) hsl[k] = 0.f;
    L1State st = {0.f, 0.f, 0.f, 0.f, 0.f, 0.f};
    float c2 = 0.f;

    const float* xb = x + (size_t)b * TSEQ * DIN;
    __syncthreads();

    #pragma unroll 1
    for (int c = 0; c < NCHUNK; ++c) {
        // ---- stage x chunk (coalesced float4) ----
        ((float4*)s_x)[tid] = ((const float4*)(xb + (size_t)c * CHUNK * DIN))[tid];
        __syncthreads();

        // ---- x-part gates: thread = (step, q); 5 rows each ----
        {
            const int stp = tid >> 2, q = tid & 3;
            const float* xs = s_x + stp * DIN;
            float x0 = xs[0],  x1 = xs[1],  x2 = xs[2],  x3 = xs[3];
            float x4 = xs[4],  x5 = xs[5],  x6 = xs[6],  x7 = xs[7];
            float x8 = xs[8],  x9 = xs[9],  xA = xs[10], xB = xs[11];
            float xC = xs[12], xD = xs[13], xE = xs[14], xF = xs[15];
            #pragma unroll
            for (int r = 0; r < 5; ++r) {
                const int rw = q * 5 + r;
                const float* wr = s_w1 + rw * DIN;
                float s = wr[0] * x0;
                s = fmaf(wr[1],  x1, s); s = fmaf(wr[2],  x2, s); s = fmaf(wr[3],  x3, s);
                s = fmaf(wr[4],  x4, s); s = fmaf(wr[5],  x5, s); s = fmaf(wr[6],  x6, s);
                s = fmaf(wr[7],  x7, s); s = fmaf(wr[8],  x8, s); s = fmaf(wr[9],  x9, s);
                s = fmaf(wr[10], xA, s); s = fmaf(wr[11], xB, s); s = fmaf(wr[12], xC, s);
                s = fmaf(wr[13], xD, s); s = fmaf(wr[14], xE, s); s = fmaf(wr[15], xF, s);
                s_gx[stp * GXS + rw] = s;
            }
        }
        __syncthreads();

        // ---- chunk preamble: L1 for the chunk's step 0 ----
        l1_step(s_gx[r1], bias1, w1h, isc1, osc1, off1, st);

        // ---- one timestep; BUF is compile-time parity ----
        #define LSTM_STEP(BUF, TT, DO_L1)                                          \
        {                                                                          \
            /* partial(t): 4 rows x 13 K, h from SGPRs */                          \
            float a0 = 0.f, a1 = 0.f, a2 = 0.f, a3 = 0.f;                          \
            _Pragma("unroll")                                                      \
            for (int kk = 0; kk < 13; ++kk) {                                      \
                a0 = fmaf(hsl[kk], wp[0][kk], a0);                                 \
                a1 = fmaf(hsl[kk], wp[1][kk], a1);                                 \
                a2 = fmaf(hsl[kk], wp[2][kk], a2);                                 \
                a3 = fmaf(hsl[kk], wp[3][kk], a3);                                 \
            }                                                                      \
            ((float4*)(&s_part[BUF][wv][0]))[lane] = make_float4(a0, a1, a2, a3);  \
            float gx_next = s_gx[(TT + 1) * GXS + r1];                             \
            __syncthreads();                                                       \
            /* combine(t): gather 4 partials for my (unit,gate) row */             \
            float p0 = s_part[BUF][0][crow];                                       \
            float p1 = s_part[BUF][1][crow];                                       \
            float p2 = s_part[BUF][2][crow];                                       \
            float p3 = s_part[BUF][3][crow];                                       \
            float pre = ((p0 + p1) + (p2 + p3)) + bias2;                           \
            pre = fmaf(st.h0, w2i[0], pre);                                        \
            pre = fmaf(st.h1, w2i[1], pre);                                        \
            pre = fmaf(st.h2, w2i[2], pre);                                        \
            pre = fmaf(st.h3, w2i[3], pre);                                        \
            pre = fmaf(st.h4, w2i[4], pre);                                        \
            if (DO_L1)                                                             \
                l1_step(gx_next, bias1, w1h, isc1, osc1, off1, st);                \
            float act2 = fmaf(osc2, fast_sigm(isc2 * pre), off2);                  \
            float v1 = qperm<0xB1>(act2);                                          \
            float v2 = qperm<0x4E>(act2);                                          \
            float v3 = qperm<0x1B>(act2);                                          \
            c2 = fmaf(v1, c2, act2 * v2);                                          \
            float hn = v3 * fast_tanh(c2);                                         \
            if (g == 0 && ureal) s_h2[u] = hn;                                     \
            _Pragma("unroll")                                                      \
            for (int k = 0; k < 13; ++k) hsl[k] = rdlane(hn, 4 * k);               \
        }

        #pragma unroll 1
        for (int tt = 0; tt < CHUNK; tt += 2) {
            LSTM_STEP(0, tt, true)
            LSTM_STEP(1, tt + 1, (tt < CHUNK - 2))
        }
        #undef LSTM_STEP
    }

    __syncthreads();
    // ---- outputs: result(256,20) @0, last(256,50) @5120 ----
    if (tid < NH2) out[BATCH * NCLS + b * NH2 + tid] = s_h2[tid];
    if (tid < NCLS) {
        float acc = bfc[tid];
        const float* wr = Wfc + tid * NH2;
        #pragma unroll
        for (int j = 0; j < NH2; ++j) acc = fmaf(s_h2[j], wr[j], acc);
        out[b * NCLS + tid] = acc;
    }
}

} // namespace

extern "C" void kernel_launch(void* const* d_in, const int* in_sizes, int n_in,
                              void* d_out, int out_size, void* d_ws, size_t ws_size,
                              hipStream_t stream) {
    (void)in_sizes; (void)n_in; (void)d_ws; (void)ws_size; (void)out_size;
    const float* x    = (const float*)d_in[0];
    const float* W1ih = (const float*)d_in[1];
    const float* W1hh = (const float*)d_in[2];
    const float* b1ih = (const float*)d_in[3];
    const float* b1hh = (const float*)d_in[4];
    const float* W2ih = (const float*)d_in[5];
    const float* W2hh = (const float*)d_in[6];
    const float* b2ih = (const float*)d_in[7];
    const float* b2hh = (const float*)d_in[8];
    const float* Wfc  = (const float*)d_in[9];
    const float* bfc  = (const float*)d_in[10];

    lstm_fused_kernel<<<dim3(BATCH), dim3(256), 0, stream>>>(
        x, W1ih, W1hh, b1ih, b1hh, W2ih, W2hh, b2ih, b2hh, Wfc, bfc,
        (float*)d_out);
}